// Round 8
// baseline (5827.170 us; speedup 1.0000x reference)
//
#include <hip/hip_runtime.h>
#include <hip/hip_bf16.h>
#include <math.h>

typedef __hip_bfloat16 bf16;

// Problem constants
constexpr int CB   = 32;    // batch
constexpr int CN   = 256;   // tokens
constexpr int CD   = 384;   // model dim (incl. time)
constexpr int CDS  = 383;   // space dim
constexpr int CH   = 6;     // heads
constexpr int CHC  = 64;    // head channels (incl. time)
constexpr int CHCS = 63;    // head space channels
constexpr int CL   = 12;    // layers
constexpr int CMH  = 1536;  // mlp hidden (incl. time)
constexpr int CMHS = 1535;
constexpr int CROWS = CB * CN;        // 8192
constexpr int CKP  = 784;             // patch vector length (14*14*4)
constexpr int CKPP = 832;             // padded patch stride (mult of 64)
constexpr int CQN  = CH * CHCS;       // 378
constexpr int CQN3 = 3 * CQN;         // 1134 (fused qkv cols)

static inline int cdiv(int a, int b){ return (a + b - 1) / b; }

// MFMA frag types
typedef short bf8_t __attribute__((ext_vector_type(8)));
typedef float f4_t  __attribute__((ext_vector_type(4)));

// fp32 -> bf16 (RNE) raw
__device__ __forceinline__ unsigned short f2bf(float f) {
    union { float f; unsigned u; } x; x.f = f;
    unsigned r = x.u + 0x7FFFu + ((x.u >> 16) & 1u);
    return (unsigned short)(r >> 16);
}
__device__ __forceinline__ float bf2f(unsigned short h) {
    union { unsigned u; float f; } x; x.u = ((unsigned)h) << 16;
    return x.f;
}

// Dual-dtype input load: isb=1 -> bf16, isb=0 -> fp32. Wave-uniform isb.
__device__ __forceinline__ float ldin(const void* p, size_t i, int isb) {
    if (isb) return __bfloat162float(((const bf16*)p)[i]);
    return ((const float*)p)[i];
}

// ---------------------------------------------------------------------------
// Dtype detector (inputs fp32 expected; bf16 fallback).
// ---------------------------------------------------------------------------
__global__ __launch_bounds__(256)
void detect_kernel(const void* __restrict__ x, int* __restrict__ flag) {
    __shared__ int red[256];
    const unsigned short* u = (const unsigned short*)x;
    int cnt = 0;
    for (int i = threadIdx.x; i < 4096; i += 256) {
        unsigned short v = u[i];
        int e = (v >> 7) & 0xFF;
        cnt += (v == 0 || (e >= 96 && e <= 142)) ? 1 : 0;
    }
    red[threadIdx.x] = cnt;
    __syncthreads();
    for (int off = 128; off > 0; off >>= 1) {
        if (threadIdx.x < off) red[threadIdx.x] += red[threadIdx.x + off];
        __syncthreads();
    }
    if (threadIdx.x == 0) flag[0] = (red[0] >= 3482) ? 1 : 0;
}

// ---------------------------------------------------------------------------
// Patchify: x[B,3,224,224] -> patches[8192, CKPP] (stride-padded) fp32
// ---------------------------------------------------------------------------
__global__ __launch_bounds__(256)
void patchify_kernel(const void* __restrict__ x, float* __restrict__ patches,
                     const int* __restrict__ flg) {
    int isb = flg[0];
    int idx = blockIdx.x * 256 + threadIdx.x;
    if (idx >= CB * 224 * 224) return;
    int col = idx % 224;
    int t   = idx / 224;
    int row = t % 224;
    int b   = t / 224;
    size_t base = ((size_t)b * 3) * 224 * 224 + (size_t)row * 224 + col;
    float r  = ldin(x, base, isb);
    float g  = ldin(x, base + 224 * 224, isb);
    float bl = ldin(x, base + 2 * 224 * 224, isb);
    float tt = sqrtf(1.0f + r * r + g * g + bl * bl);
    int gi = row / 14, pi = row % 14, gj = col / 14, pj = col % 14;
    int p = gi * 16 + gj;
    float* dp = patches + ((size_t)(b * CN + p)) * CKPP + (pi * 14 + pj) * 4;
    *(float4*)dp = make_float4(tt, r, g, bl);
}

// zero the pad region [784, 832) of each patch row
__global__ __launch_bounds__(256)
void padzero_kernel(float* __restrict__ patches) {
    int idx = blockIdx.x * 256 + threadIdx.x;
    if (idx >= CROWS * (CKPP - CKP)) return;
    int row = idx / (CKPP - CKP), off = idx % (CKPP - CKP);
    patches[(size_t)row * CKPP + CKP + off] = 0.0f;
}

// ---------------------------------------------------------------------------
// MFMA GEMM v2: C[M,N] = A[M,lda(K)] @ W[K,N] + bias. Tile 64x64, BK=64,
// register prefetch of next tile overlapped with MFMA. wmode=0: W row-major
// [K,N] at woff (Wb/bb used). wmode=1: fused QKV, col c -> tensor c/378 of
// {Wq,Wk,Wv} ([H,384,63] each at woff), col rem h*63+e; bias {bq,bk,bv}.
// lda must be mult of 64 (A reads unguarded); W guarded iff K%64 != 0.
// grid (cdiv(N,64), M/64), 256 thr.
// ---------------------------------------------------------------------------
__global__ __launch_bounds__(256)
void gemm_kernel(const float* __restrict__ A,
                 const void* __restrict__ Wb, const void* __restrict__ Wc,
                 const void* __restrict__ Wd, size_t woff,
                 const void* __restrict__ bb, const void* __restrict__ bc,
                 const void* __restrict__ bd, size_t boff,
                 float* __restrict__ C, int N, int K, int lda, int wmode,
                 const int* __restrict__ flg) {
    int isb = flg[0];
    int kgrd = (K & 63) != 0;
    __shared__ __align__(16) short Ablk[2][4][64][8];   // [sub][mtile][slot][j]
    __shared__ __align__(16) short Bblk[2][4][64][8];
    int tid = threadIdx.x;
    int wave = tid >> 6, lane = tid & 63;
    int bm = blockIdx.y * 64, bn = blockIdx.x * 64;
    int wm = (wave & 1) * 2, wn = (wave >> 1) * 2;
    f4_t acc[2][2] = {};

    // A staging: mA = tid>>2, octets kqA and kqA+4
    int mA = tid >> 2, kqA = tid & 3;
    const float* arow = A + (size_t)(bm + mA) * lda;
    // B staging: col nl, octets kqB and kqB+4
    int nl = tid & 63;
    int nB = bn + nl;
    int kqB = tid >> 6;
    bool nval = nB < N;
    int ncl = nval ? nB : 0;
    const void* Wsel; size_t wcol; int wstr;
    if (wmode) {
        int which = (ncl >= 756) ? 2 : (ncl >= 378 ? 1 : 0);
        int rem = ncl - which * 378;
        int h = rem / 63, e = rem - h * 63;
        Wsel = which == 0 ? Wb : (which == 1 ? Wc : Wd);
        wcol = woff + (size_t)h * CD * 63 + e; wstr = 63;
    } else { Wsel = Wb; wcol = woff + ncl; wstr = N; }

    float4 aR[4];
    float  bR[16];
    auto loadA = [&](int k0) {
        int ka = k0 + kqA * 8, kb2 = k0 + (kqA + 4) * 8;
        aR[0] = *(const float4*)(arow + ka);
        aR[1] = *(const float4*)(arow + ka + 4);
        aR[2] = *(const float4*)(arow + kb2);
        aR[3] = *(const float4*)(arow + kb2 + 4);
    };
    auto loadB = [&](int k0) {
        #pragma unroll
        for (int o = 0; o < 2; o++)
            #pragma unroll
            for (int jj = 0; jj < 8; jj++) {
                int kr = k0 + (kqB + o * 4) * 8 + jj;
                float wv = 0.0f;
                if (nval && (!kgrd || kr < K))
                    wv = ldin(Wsel, wcol + (size_t)kr * wstr, isb);
                bR[o * 8 + jj] = wv;
            }
    };
    auto storeLDS = [&]() {
        #pragma unroll
        for (int o = 0; o < 2; o++) {
            int q = kqA + o * 4;
            bf8_t av;
            float4 f0 = aR[o * 2], f1 = aR[o * 2 + 1];
            av[0]=(short)f2bf(f0.x); av[1]=(short)f2bf(f0.y);
            av[2]=(short)f2bf(f0.z); av[3]=(short)f2bf(f0.w);
            av[4]=(short)f2bf(f1.x); av[5]=(short)f2bf(f1.y);
            av[6]=(short)f2bf(f1.z); av[7]=(short)f2bf(f1.w);
            *(bf8_t*)&Ablk[q >> 2][mA >> 4][(mA & 15) | ((q & 3) << 4)][0] = av;
        }
        #pragma unroll
        for (int o = 0; o < 2; o++) {
            int q = kqB + o * 4;
            bf8_t bv;
            #pragma unroll
            for (int jj = 0; jj < 8; jj++) bv[jj] = (short)f2bf(bR[o * 8 + jj]);
            *(bf8_t*)&Bblk[q >> 2][nl >> 4][(nl & 15) | ((q & 3) << 4)][0] = bv;
        }
    };

    loadA(0); loadB(0);
    for (int k0 = 0; k0 < K; k0 += 64) {
        storeLDS();
        __syncthreads();
        if (k0 + 64 < K) { loadA(k0 + 64); loadB(k0 + 64); }
        #pragma unroll
        for (int sub = 0; sub < 2; sub++) {
            bf8_t a0 = *(const bf8_t*)&Ablk[sub][wm    ][lane][0];
            bf8_t a1 = *(const bf8_t*)&Ablk[sub][wm + 1][lane][0];
            bf8_t b0 = *(const bf8_t*)&Bblk[sub][wn    ][lane][0];
            bf8_t b1 = *(const bf8_t*)&Bblk[sub][wn + 1][lane][0];
            acc[0][0] = __builtin_amdgcn_mfma_f32_16x16x32_bf16(a0, b0, acc[0][0], 0, 0, 0);
            acc[0][1] = __builtin_amdgcn_mfma_f32_16x16x32_bf16(a0, b1, acc[0][1], 0, 0, 0);
            acc[1][0] = __builtin_amdgcn_mfma_f32_16x16x32_bf16(a1, b0, acc[1][0], 0, 0, 0);
            acc[1][1] = __builtin_amdgcn_mfma_f32_16x16x32_bf16(a1, b1, acc[1][1], 0, 0, 0);
        }
        __syncthreads();
    }
    int colq = lane & 15, rowq = (lane >> 4) * 4;
    #pragma unroll
    for (int ni = 0; ni < 2; ni++) {
        int col = bn + (wn + ni) * 16 + colq;
        if (col >= N) continue;
        float bbv;
        if (wmode) {
            int wh = (col >= 756) ? 2 : (col >= 378 ? 1 : 0);
            int rm = col - wh * 378;
            const void* bp = wh == 0 ? bb : (wh == 1 ? bc : bd);
            bbv = ldin(bp, boff + rm, isb);
        } else bbv = ldin(bb, boff + col, isb);
        #pragma unroll
        for (int mi = 0; mi < 2; mi++) {
            int row = bm + (wm + mi) * 16 + rowq;
            #pragma unroll
            for (int r = 0; r < 4; r++)
                C[(size_t)(row + r) * N + col] = acc[mi][ni][r] + bbv;
        }
    }
}

// ---------------------------------------------------------------------------
// add_time rows (+optional GELU). src [M,NS], dst [M,NS+1].
// ---------------------------------------------------------------------------
__global__ __launch_bounds__(256)
void add_time_rows_kernel(const float* __restrict__ src, float* __restrict__ dst,
                          int NS, int do_gelu) {
    int row = blockIdx.x;
    int tid = threadIdx.x;
    __shared__ float buf[1536];
    __shared__ float red[256];
    const float* sr = src + (size_t)row * NS;
    float ss = 0.0f;
    for (int j = tid; j < NS; j += 256) {
        float vv = sr[j];
        if (do_gelu) {
            float x3 = vv * vv * vv;
            vv = 0.5f * vv * (1.0f + tanhf(0.7978845608028654f * (vv + 0.044715f * x3)));
        }
        buf[j] = vv;
        ss += vv * vv;
    }
    red[tid] = ss;
    __syncthreads();
    for (int off = 128; off > 0; off >>= 1) {
        if (tid < off) red[tid] += red[tid + off];
        __syncthreads();
    }
    float t = sqrtf(1.0f + red[0]);
    float* dr = dst + (size_t)row * (NS + 1);
    if (tid == 0) dr[0] = t;
    for (int j = tid; j < NS; j += 256) dr[1 + j] = buf[j];
}

// ---------------------------------------------------------------------------
// Fused: out = lnormalize(base + scale * add_time(src)); src [M,383].
// ---------------------------------------------------------------------------
__global__ __launch_bounds__(256)
void addtime_lresnet_kernel(const float* __restrict__ src,
                            const float* __restrict__ base, float scale,
                            float* __restrict__ out) {
    int row = blockIdx.x;
    int tid = threadIdx.x;
    const float* sr = src + (size_t)row * CDS;
    const float* br = base + (size_t)row * CD;
    __shared__ float red[256];
    float s0 = (tid > 0) ? sr[tid - 1] : 0.0f;
    float s1 = (tid < 128) ? sr[tid + 255] : 0.0f;
    red[tid] = s0 * s0 + s1 * s1;
    __syncthreads();
    for (int off = 128; off > 0; off >>= 1) {
        if (tid < off) red[tid] += red[tid + off];
        __syncthreads();
    }
    float t = sqrtf(1.0f + red[0]);
    __syncthreads();
    float y0 = (tid == 0) ? t : s0;
    float z0 = br[tid] + scale * y0;
    float z1 = (tid < 128) ? br[tid + 256] + scale * s1 : 0.0f;
    float c = (tid == 0) ? z0 * z0 : -z0 * z0;
    c -= z1 * z1;
    red[tid] = c;
    __syncthreads();
    for (int off = 128; off > 0; off >>= 1) {
        if (tid < off) red[tid] += red[tid + off];
        __syncthreads();
    }
    float rd = 1.0f / sqrtf(fmaxf(red[0], 1e-8f));
    float* orow = out + (size_t)row * CD;
    orow[tid] = z0 * rd;
    if (tid < 128) orow[256 + tid] = z1 * rd;
}

// ---------------------------------------------------------------------------
// Lorentz layernorm: x[M,384] -> out[M,384]
// ---------------------------------------------------------------------------
__global__ __launch_bounds__(256)
void llayernorm_kernel(const float* __restrict__ x, const void* __restrict__ g,
                       size_t goff, const void* __restrict__ b, size_t boff,
                       float* __restrict__ out, const int* __restrict__ flg) {
    int isb = flg[0];
    int row = blockIdx.x;
    int tid = threadIdx.x;
    const float* xr = x + (size_t)row * CD;
    __shared__ float red[256];
    __shared__ float red2[256];
    int j0 = tid, j1 = tid + 256;
    float v0 = xr[1 + j0];
    float v1 = (j1 < CDS) ? xr[1 + j1] : 0.0f;
    red[tid]  = v0 + v1;
    red2[tid] = v0 * v0 + v1 * v1;
    __syncthreads();
    for (int off = 128; off > 0; off >>= 1) {
        if (tid < off) { red[tid] += red[tid + off]; red2[tid] += red2[tid + off]; }
        __syncthreads();
    }
    float mu  = red[0] * (1.0f / 383.0f);
    float var = red2[0] * (1.0f / 383.0f) - mu * mu;
    __syncthreads();
    float rstd = rsqrtf(var + 1e-5f);
    float y0 = (v0 - mu) * rstd * ldin(g, goff + j0, isb) + ldin(b, boff + j0, isb);
    float y1 = 0.0f;
    if (j1 < CDS) y1 = (v1 - mu) * rstd * ldin(g, goff + j1, isb) + ldin(b, boff + j1, isb);
    red[tid] = y0 * y0 + y1 * y1;
    __syncthreads();
    for (int off = 128; off > 0; off >>= 1) {
        if (tid < off) red[tid] += red[tid + off];
        __syncthreads();
    }
    float t = sqrtf(1.0f + red[0]);
    float* orow = out + (size_t)row * CD;
    orow[1 + j0] = y0;
    if (j1 < CDS) orow[1 + j1] = y1;
    if (tid == 0) orow[0] = t;
}

// lresnet vs broadcast dual-dtype pe (scale = 1)
__global__ __launch_bounds__(256)
void lresnet_pe_kernel(const float* __restrict__ x, const void* __restrict__ pe,
                       float* __restrict__ out, const int* __restrict__ flg) {
    int isb = flg[0];
    int row = blockIdx.x;
    int tid = threadIdx.x;
    const float* xr = x + (size_t)row * CD;
    size_t pb = (size_t)(row & (CN - 1)) * CD;
    __shared__ float red[256];
    float z0 = xr[tid] + ldin(pe, pb + tid, isb);
    float z1 = 0.0f;
    float c = (tid == 0) ? z0 * z0 : -z0 * z0;
    if (tid < 128) { z1 = xr[256 + tid] + ldin(pe, pb + 256 + tid, isb); c -= z1 * z1; }
    red[tid] = c;
    __syncthreads();
    for (int off = 128; off > 0; off >>= 1) {
        if (tid < off) red[tid] += red[tid + off];
        __syncthreads();
    }
    float rd = 1.0f / sqrtf(fmaxf(red[0], 1e-8f));
    float* orow = out + (size_t)row * CD;
    orow[tid] = z0 * rd;
    if (tid < 128) orow[256 + tid] = z1 * rd;
}

// ---------------------------------------------------------------------------
// qkv finish (fused): src[8192,1134] -> qkv[3][B,H,N,64] with add_time.
// grid (8192, 18): blockIdx.y = which*6 + h.
// ---------------------------------------------------------------------------
__global__ __launch_bounds__(64)
void qkv_finish_kernel(const float* __restrict__ src, float* __restrict__ qkv,
                       size_t fh) {
    int row = blockIdx.x;
    int hs  = blockIdx.y;              // 0..17
    int which = hs / 6, h = hs % 6;
    int e   = threadIdx.x;
    float y = (e < CHCS) ? src[(size_t)row * CQN3 + hs * 63 + e] : 0.0f;
    float ss = y * y;
    #pragma unroll
    for (int off = 32; off > 0; off >>= 1) ss += __shfl_down(ss, off);
    float t = sqrtf(1.0f + __shfl(ss, 0));
    int b = row >> 8, n = row & 255;
    float* dr = qkv + which * fh + (((size_t)(b * CH + h)) * CN + n) * CHC;
    if (e < CHCS) dr[1 + e] = y;
    if (e == 0)   dr[0] = t;
}

// ---------------------------------------------------------------------------
// Attention v4 (MFMA, split-precision) — unchanged from round 7 (passing).
// ---------------------------------------------------------------------------
__global__ __launch_bounds__(256)
void attn_kernel(const float* __restrict__ q, const float* __restrict__ k,
                 const float* __restrict__ v, float* __restrict__ attcat) {
    __shared__ __align__(16) unsigned char smem[65536];
    unsigned short* Aqh = (unsigned short*)smem;
    unsigned short* Aql = (unsigned short*)(smem + 8192);
    unsigned short* Bk  = (unsigned short*)(smem + 16384);
    unsigned short* Pf  = (unsigned short*)smem;
    unsigned short* Bv  = (unsigned short*)(smem + 32768);
    int qc = blockIdx.x, bh = blockIdx.y;
    int h = bh % CH, b = bh / CH;
    int tid = threadIdx.x, wave = tid >> 6, lane = tid & 63;
    const float* qb = q + ((size_t)bh * CN + qc * 64) * CHC;
    const float* kb = k + (size_t)bh * CN * CHC;
    const float* vb = v + (size_t)bh * CN * CHC;

    #pragma unroll
    for (int it = 0; it < 4; it++) {
        int flat = it * 256 + tid;
        int ql = flat >> 4;
        int c4 = (flat & 15) * 4;
        float4 f = *(const float4*)(qb + ql * CHC + c4);
        if (c4 == 0) f.x = -f.x;
        int mt = ql >> 4, ks = c4 >> 5;
        int lp = (ql & 15) | (((c4 >> 3) & 3) << 4);
        int off = (((mt * 2 + ks) * 64 + lp) * 8) + (c4 & 7);
        float fv[4] = {f.x, f.y, f.z, f.w};
        #pragma unroll
        for (int i = 0; i < 4; i++) {
            unsigned short hi = f2bf(fv[i]);
            Aqh[off + i] = hi;
            Aql[off + i] = f2bf(fv[i] - bf2f(hi));
        }
    }
    #pragma unroll
    for (int it = 0; it < 16; it++) {
        int flat = it * 256 + tid;
        int tk = flat >> 4;
        int c4 = (flat & 15) * 4;
        float4 f = *(const float4*)(kb + tk * CHC + c4);
        int nt = tk >> 4, ks = c4 >> 5;
        int lp = (tk & 15) | (((c4 >> 3) & 3) << 4);
        unsigned short* dst = Bk + (((nt * 2 + ks) * 64 + lp) * 8) + (c4 & 7);
        dst[0] = f2bf(f.x); dst[1] = f2bf(f.y); dst[2] = f2bf(f.z); dst[3] = f2bf(f.w);
    }
    __syncthreads();
    f4_t s[16];
    #pragma unroll
    for (int nt = 0; nt < 16; nt++) s[nt] = (f4_t){0.0f, 0.0f, 0.0f, 0.0f};
    bf8_t ah0 = *(const bf8_t*)(Aqh + ((wave * 2 + 0) * 64 + lane) * 8);
    bf8_t ah1 = *(const bf8_t*)(Aqh + ((wave * 2 + 1) * 64 + lane) * 8);
    bf8_t al0 = *(const bf8_t*)(Aql + ((wave * 2 + 0) * 64 + lane) * 8);
    bf8_t al1 = *(const bf8_t*)(Aql + ((wave * 2 + 1) * 64 + lane) * 8);
    #pragma unroll
    for (int nt = 0; nt < 16; nt++) {
        bf8_t b0 = *(const bf8_t*)(Bk + ((nt * 2 + 0) * 64 + lane) * 8);
        bf8_t b1 = *(const bf8_t*)(Bk + ((nt * 2 + 1) * 64 + lane) * 8);
        s[nt] = __builtin_amdgcn_mfma_f32_16x16x32_bf16(ah0, b0, s[nt], 0, 0, 0);
        s[nt] = __builtin_amdgcn_mfma_f32_16x16x32_bf16(ah1, b1, s[nt], 0, 0, 0);
        s[nt] = __builtin_amdgcn_mfma_f32_16x16x32_bf16(al0, b0, s[nt], 0, 0, 0);
        s[nt] = __builtin_amdgcn_mfma_f32_16x16x32_bf16(al1, b1, s[nt], 0, 0, 0);
    }
    float mx[4] = {-1e30f, -1e30f, -1e30f, -1e30f};
    #pragma unroll
    for (int nt = 0; nt < 16; nt++)
        #pragma unroll
        for (int r = 0; r < 4; r++) mx[r] = fmaxf(mx[r], s[nt][r]);
    #pragma unroll
    for (int off = 1; off < 16; off <<= 1)
        #pragma unroll
        for (int r = 0; r < 4; r++) mx[r] = fmaxf(mx[r], __shfl_xor(mx[r], off));
    float sm[4] = {0.0f, 0.0f, 0.0f, 0.0f};
    #pragma unroll
    for (int nt = 0; nt < 16; nt++)
        #pragma unroll
        for (int r = 0; r < 4; r++) {
            float e = __expf(0.25f * (s[nt][r] - mx[r]));
            s[nt][r] = e; sm[r] += e;
        }
    #pragma unroll
    for (int off = 1; off < 16; off <<= 1)
        #pragma unroll
        for (int r = 0; r < 4; r++) sm[r] += __shfl_xor(sm[r], off);
    #pragma unroll
    for (int r = 0; r < 4; r++) sm[r] = 1.0f / sm[r];
    #pragma unroll
    for (int nt = 0; nt < 16; nt++)
        #pragma unroll
        for (int r = 0; r < 4; r++) s[nt][r] *= sm[r];

    int colq = lane & 15, quad = lane >> 4;
    auto writePf = [&](int lo) {
        #pragma unroll
        for (int nt = 0; nt < 16; nt++) {
            int key = nt * 16 + colq;
            int ks = key >> 5;
            #pragma unroll
            for (int r = 0; r < 4; r++) {
                int qrow = quad * 4 + r;
                int lp = (qrow & 15) | (((key >> 3) & 3) << 4);
                float p = s[nt][r];
                unsigned short hi = f2bf(p);
                unsigned short w = lo ? f2bf(p - bf2f(hi)) : hi;
                Pf[((wave * 8 + ks) * 64 + lp) * 8 + (key & 7)] = w;
            }
        }
    };
    auto stageBv = [&](int lo) {
        #pragma unroll
        for (int it = 0; it < 16; it++) {
            int flat = it * 256 + tid;
            int tk = flat >> 4;
            int c4 = (flat & 15) * 4;
            float4 f = *(const float4*)(vb + tk * CHC + c4);
            int ks = tk >> 5, jj = tk & 7, kq = (tk >> 3) & 3;
            int nt = c4 >> 4;
            int lq = (c4 & 15) | (kq << 4);
            unsigned short* base = Bv + ((nt * 8 + ks) * 64) * 8 + jj;
            float fv[4] = {f.x, f.y, f.z, f.w};
            #pragma unroll
            for (int i = 0; i < 4; i++) {
                unsigned short hi = f2bf(fv[i]);
                base[(lq + i) * 8] = lo ? f2bf(fv[i] - bf2f(hi)) : hi;
            }
        }
    };
    f4_t o[4] = {};
    auto pvpass = [&]() {
        #pragma unroll
        for (int ks = 0; ks < 8; ks++) {
            bf8_t pa = *(const bf8_t*)(Pf + ((wave * 8 + ks) * 64 + lane) * 8);
            #pragma unroll
            for (int nt = 0; nt < 4; nt++) {
                bf8_t vv = *(const bf8_t*)(Bv + ((nt * 8 + ks) * 64 + lane) * 8);
                o[nt] = __builtin_amdgcn_mfma_f32_16x16x32_bf16(pa, vv, o[nt], 0, 0, 0);
            }
        }
    };

    __syncthreads();
    writePf(0); stageBv(0);
    __syncthreads();
    pvpass();
    __syncthreads();
    writePf(1);
    __syncthreads();
    pvpass();
    __syncthreads();
    writePf(0); stageBv(1);
    __syncthreads();
    pvpass();

    {
        float nrm[4] = {0.0f, 0.0f, 0.0f, 0.0f};
        #pragma unroll
        for (int nt = 0; nt < 4; nt++) {
            float sgn = (nt == 0 && colq == 0) ? 1.0f : -1.0f;
            #pragma unroll
            for (int r = 0; r < 4; r++) nrm[r] += sgn * o[nt][r] * o[nt][r];
        }
        #pragma unroll
        for (int off = 1; off < 16; off <<= 1)
            #pragma unroll
            for (int r = 0; r < 4; r++) nrm[r] += __shfl_xor(nrm[r], off);
        #pragma unroll
        for (int r = 0; r < 4; r++) {
            float d = 1.0f / sqrtf(fmaxf(nrm[r], 1e-8f));
            int qg = qc * 64 + wave * 16 + quad * 4 + r;
            float* orow = attcat + ((size_t)b * CN + qg) * CD + h * CHC;
            #pragma unroll
            for (int nt = 0; nt < 4; nt++)
                orow[nt * 16 + colq] = o[nt][r] * d;
        }
    }
}

// ---------------------------------------------------------------------------
// mean-pool over tokens + lnormalize -> emb[32,384]
// ---------------------------------------------------------------------------
__global__ __launch_bounds__(256)
void meanpool_kernel(const float* __restrict__ hbuf, float* __restrict__ emb) {
    int b = blockIdx.x;
    int tid = threadIdx.x;
    const float* hb = hbuf + (size_t)b * CN * CD;
    float s0 = 0.0f, s1 = 0.0f;
    for (int n = 0; n < CN; n++) {
        s0 += hb[(size_t)n * CD + tid];
        if (tid < 128) s1 += hb[(size_t)n * CD + 256 + tid];
    }
    s0 *= (1.0f / 256.0f);
    s1 *= (1.0f / 256.0f);
    __shared__ float red[256];
    float c = (tid == 0) ? s0 * s0 : -s0 * s0;
    if (tid < 128) c -= s1 * s1;
    red[tid] = c;
    __syncthreads();
    for (int off = 128; off > 0; off >>= 1) {
        if (tid < off) red[tid] += red[tid + off];
        __syncthreads();
    }
    float rd = 1.0f / sqrtf(fmaxf(red[0], 1e-8f));
    emb[(size_t)b * CD + tid] = s0 * rd;
    if (tid < 128) emb[(size_t)b * CD + 256 + tid] = s1 * rd;
}

// ---------------------------------------------------------------------------
// MLR head precompute v2: wave-per-class, coalesced. grid (250), 256 thr.
// ---------------------------------------------------------------------------
__global__ __launch_bounds__(256)
void head_pre_kernel(const void* __restrict__ mlra, const void* __restrict__ mlrz,
                     float* __restrict__ wt, float* __restrict__ beta,
                     float* __restrict__ cha, const int* __restrict__ flg) {
    int isb = flg[0];
    int wave = threadIdx.x >> 6, lane = threadIdx.x & 63;
    int c = blockIdx.x * 4 + wave;          // < 1000
    float S = 0.0f;
    for (int j = lane; j < CDS; j += 64) {
        float zz = ldin(mlrz, (size_t)c * CDS + j, isb);
        S += zz * zz;
    }
    #pragma unroll
    for (int off = 32; off > 0; off >>= 1) S += __shfl_xor(S, off);
    if (lane == 0) {
        float a  = ldin(mlra, c, isb);
        float sh = sinhf(a), ch = coshf(a);
        float zn = sqrtf(S + 1e-8f);
        float w  = sh * zn;
        wt[c]  = w;
        cha[c] = ch;
        beta[c] = sqrtf(fmaxf(ch * ch * S - w * w, 1e-8f));
    }
}

__global__ __launch_bounds__(256)
void head_logits_kernel(const float* __restrict__ emb, const void* __restrict__ mlrz,
                        const float* __restrict__ wt, const float* __restrict__ beta,
                        const float* __restrict__ cha, void* __restrict__ out,
                        const int* __restrict__ flg) {
    int isb = flg[0];
    int b = blockIdx.x;
    int c = blockIdx.y * 256 + threadIdx.x;
    __shared__ float es[CD];
    for (int j = threadIdx.x; j < CD; j += 256) es[j] = emb[(size_t)b * CD + j];
    __syncthreads();
    if (c < 1000) {
        float dotv = 0.0f;
        for (int j = 0; j < CDS; j++)
            dotv += es[1 + j] * ldin(mlrz, (size_t)c * CDS + j, isb);
        float alpha = -es[0] * wt[c] + cha[c] * dotv;
        float be = beta[c];
        float lg = be * asinhf(alpha / be);
        if (isb) ((bf16*)out)[(size_t)b * 1000 + c] = __float2bfloat16(lg);
        else     ((float*)out)[(size_t)b * 1000 + c] = lg;
    }
}

// ---------------------------------------------------------------------------
// Orchestration.
// ---------------------------------------------------------------------------
extern "C" void kernel_launch(void* const* d_in, const int* in_sizes, int n_in,
                              void* d_out, int out_size, void* d_ws, size_t ws_size,
                              hipStream_t stream) {
    const void* x      = d_in[0];
    const void* patchW = d_in[1];
    const void* patchB = d_in[2];
    const void* pe     = d_in[3];
    const void* ln1g   = d_in[4];
    const void* ln1b   = d_in[5];
    const void* ln2g   = d_in[6];
    const void* ln2b   = d_in[7];
    const void* Wq     = d_in[8];
    const void* bq     = d_in[9];
    const void* Wk     = d_in[10];
    const void* bk     = d_in[11];
    const void* Wv     = d_in[12];
    const void* bv     = d_in[13];
    const void* Wo     = d_in[14];
    const void* bo     = d_in[15];
    const void* W1     = d_in[16];
    const void* b1     = d_in[17];
    const void* W2     = d_in[18];
    const void* b2     = d_in[19];
    const void* mlra   = d_in[20];
    const void* mlrz   = d_in[21];

    float* ws = (float*)d_ws;
    const size_t FH = (size_t)CROWS * CD;
    float* hbuf   = ws;
    float* xln    = ws + FH;
    float* big1   = ws + 2 * FH;   // 4*FH: patches(8192x832=27MB ok) / gemm outs
    float* big2   = ws + 6 * FH;   // 4*FH: qkv(3*FH)+attcat / mlp hidden
    float* qb     = big2;
    float* vb     = big2 + 2 * FH;
    float* attcat = big2 + 3 * FH;
    float* emb    = ws + 10 * FH;
    float* wt     = emb + (size_t)CB * CD;
    float* beta   = wt + 1000;
    float* cha    = beta + 1000;
    int*   flag   = (int*)(cha + 1000);

    const size_t WQKV = (size_t)CH * CD * CHCS;
    const float* kb = big2 + FH;

    detect_kernel<<<1, 256, 0, stream>>>(x, flag);

    // patch embed (patches padded to stride 832)
    patchify_kernel<<<cdiv(CB * 224 * 224, 256), 256, 0, stream>>>(x, big1, flag);
    padzero_kernel<<<cdiv(CROWS * (CKPP - CKP), 256), 256, 0, stream>>>(big1);
    gemm_kernel<<<dim3(cdiv(CDS, 64), CROWS / 64), 256, 0, stream>>>(
        big1, patchW, nullptr, nullptr, 0, patchB, nullptr, nullptr, 0,
        big2, CDS, CKP, CKPP, 0, flag);
    add_time_rows_kernel<<<CROWS, 256, 0, stream>>>(big2, xln, CDS, 0);
    lresnet_pe_kernel<<<CROWS, 256, 0, stream>>>(xln, pe, hbuf, flag);

    for (int l = 0; l < CL; l++) {
        // --- attention block (residual base = LN1 output xln) ---
        llayernorm_kernel<<<CROWS, 256, 0, stream>>>(
            hbuf, ln1g, (size_t)l * CDS, ln1b, (size_t)l * CDS, xln, flag);
        gemm_kernel<<<dim3(cdiv(CQN3, 64), CROWS / 64), 256, 0, stream>>>(
            xln, Wq, Wk, Wv, (size_t)l * WQKV, bq, bk, bv, (size_t)l * CQN,
            big1, CQN3, CD, CD, 1, flag);
        qkv_finish_kernel<<<dim3(CROWS, 18), 64, 0, stream>>>(big1, qb, FH);
        attn_kernel<<<dim3(4, CB * CH), 256, 0, stream>>>(qb, kb, vb, attcat);
        gemm_kernel<<<dim3(cdiv(CDS, 64), CROWS / 64), 256, 0, stream>>>(
            attcat, Wo, nullptr, nullptr, (size_t)l * CD * CDS,
            bo, nullptr, nullptr, (size_t)l * CDS, big1, CDS, CD, CD, 0, flag);
        addtime_lresnet_kernel<<<CROWS, 256, 0, stream>>>(big1, xln, 27.5f, hbuf);
        // --- mlp block (residual base = hbuf) ---
        llayernorm_kernel<<<CROWS, 256, 0, stream>>>(
            hbuf, ln2g, (size_t)l * CDS, ln2b, (size_t)l * CDS, xln, flag);
        gemm_kernel<<<dim3(cdiv(CMHS, 64), CROWS / 64), 256, 0, stream>>>(
            xln, W1, nullptr, nullptr, (size_t)l * CD * CMHS,
            b1, nullptr, nullptr, (size_t)l * CMHS, big1, CMHS, CD, CD, 0, flag);
        add_time_rows_kernel<<<CROWS, 256, 0, stream>>>(big1, big2, CMHS, 1);
        gemm_kernel<<<dim3(cdiv(CDS, 64), CROWS / 64), 256, 0, stream>>>(
            big2, W2, nullptr, nullptr, (size_t)l * CMH * CDS,
            b2, nullptr, nullptr, (size_t)l * CDS, big1, CDS, CMH, CMH, 0, flag);
        addtime_lresnet_kernel<<<CROWS, 256, 0, stream>>>(big1, hbuf, 27.5f, hbuf);
    }

    // head
    meanpool_kernel<<<CB, 256, 0, stream>>>(hbuf, emb);
    head_pre_kernel<<<250, 256, 0, stream>>>(mlra, mlrz, wt, beta, cha, flag);
    head_logits_kernel<<<dim3(CB, 4), 256, 0, stream>>>(emb, mlrz, wt, beta, cha, d_out, flag);
}

// Round 9
// 4545.040 us; speedup vs baseline: 1.2821x; 1.2821x over previous
//
#include <hip/hip_runtime.h>
#include <hip/hip_bf16.h>
#include <math.h>

typedef __hip_bfloat16 bf16;

// Problem constants
constexpr int CB   = 32;    // batch
constexpr int CN   = 256;   // tokens
constexpr int CD   = 384;   // model dim (incl. time)
constexpr int CDS  = 383;   // space dim
constexpr int CH   = 6;     // heads
constexpr int CHC  = 64;    // head channels (incl. time)
constexpr int CHCS = 63;    // head space channels
constexpr int CL   = 12;    // layers
constexpr int CMH  = 1536;  // mlp hidden (incl. time)
constexpr int CMHS = 1535;
constexpr int CROWS = CB * CN;        // 8192
constexpr int CKP  = 784;             // patch vector length (14*14*4)
constexpr int CKPP = 832;             // padded patch stride (mult of 64)
constexpr int CQN  = CH * CHCS;       // 378
constexpr int CQN3 = 3 * CQN;         // 1134 (fused qkv cols)

static inline int cdiv(int a, int b){ return (a + b - 1) / b; }

// MFMA frag types
typedef short bf8_t __attribute__((ext_vector_type(8)));
typedef float f4_t  __attribute__((ext_vector_type(4)));

// fp32 -> bf16 (RNE) raw
__device__ __forceinline__ unsigned short f2bf(float f) {
    union { float f; unsigned u; } x; x.f = f;
    unsigned r = x.u + 0x7FFFu + ((x.u >> 16) & 1u);
    return (unsigned short)(r >> 16);
}
__device__ __forceinline__ float bf2f(unsigned short h) {
    union { unsigned u; float f; } x; x.u = ((unsigned)h) << 16;
    return x.f;
}

// Dual-dtype input load: isb=1 -> bf16, isb=0 -> fp32. Wave-uniform isb.
__device__ __forceinline__ float ldin(const void* p, size_t i, int isb) {
    if (isb) return __bfloat162float(((const bf16*)p)[i]);
    return ((const float*)p)[i];
}

// ---------------------------------------------------------------------------
// Dtype detector (inputs fp32 expected; bf16 fallback).
// ---------------------------------------------------------------------------
__global__ __launch_bounds__(256)
void detect_kernel(const void* __restrict__ x, int* __restrict__ flag) {
    __shared__ int red[256];
    const unsigned short* u = (const unsigned short*)x;
    int cnt = 0;
    for (int i = threadIdx.x; i < 4096; i += 256) {
        unsigned short v = u[i];
        int e = (v >> 7) & 0xFF;
        cnt += (v == 0 || (e >= 96 && e <= 142)) ? 1 : 0;
    }
    red[threadIdx.x] = cnt;
    __syncthreads();
    for (int off = 128; off > 0; off >>= 1) {
        if (threadIdx.x < off) red[threadIdx.x] += red[threadIdx.x + off];
        __syncthreads();
    }
    if (threadIdx.x == 0) flag[0] = (red[0] >= 3482) ? 1 : 0;
}

// ---------------------------------------------------------------------------
// Patchify: x[B,3,224,224] -> patches[8192, CKPP] bf16 (stride-padded)
// ---------------------------------------------------------------------------
__global__ __launch_bounds__(256)
void patchify_kernel(const void* __restrict__ x, unsigned short* __restrict__ patches,
                     const int* __restrict__ flg) {
    int isb = flg[0];
    int idx = blockIdx.x * 256 + threadIdx.x;
    if (idx >= CB * 224 * 224) return;
    int col = idx % 224;
    int t   = idx / 224;
    int row = t % 224;
    int b   = t / 224;
    size_t base = ((size_t)b * 3) * 224 * 224 + (size_t)row * 224 + col;
    float r  = ldin(x, base, isb);
    float g  = ldin(x, base + 224 * 224, isb);
    float bl = ldin(x, base + 2 * 224 * 224, isb);
    float tt = sqrtf(1.0f + r * r + g * g + bl * bl);
    int gi = row / 14, pi = row % 14, gj = col / 14, pj = col % 14;
    int p = gi * 16 + gj;
    unsigned short* dp = patches + ((size_t)(b * CN + p)) * CKPP + (pi * 14 + pj) * 4;
    ushort4 w = make_ushort4(f2bf(tt), f2bf(r), f2bf(g), f2bf(bl));
    *(ushort4*)dp = w;
}

// zero the pad region [784, 832) of each patch row (bf16)
__global__ __launch_bounds__(256)
void padzero_kernel(unsigned short* __restrict__ patches) {
    int idx = blockIdx.x * 256 + threadIdx.x;
    if (idx >= CROWS * (CKPP - CKP)) return;
    int row = idx / (CKPP - CKP), off = idx % (CKPP - CKP);
    patches[(size_t)row * CKPP + CKP + off] = 0;
}

// ---------------------------------------------------------------------------
// MFMA GEMM v3: C[M,N] = A[M,lda] @ W[K,N] + bias. A is bf16 (pre-converted
// by producers — bit-identical to on-the-fly RNE). Tile 64x64, BK=32
// (round-7 structure: BK=64+prefetch regressed — latency can't be hidden at
// 8 MFMA/barrier; see round-8 counters). wmode=0: W row-major [K,N] at woff.
// wmode=1: fused QKV col c -> tensor c/378 of {Wq,Wk,Wv}, rem h*63+e.
// lda mult of 64 (A unguarded); W k-guarded iff K%32!=0 (K=784 case).
// grid (cdiv(N,64), M/64), 256 thr.
// ---------------------------------------------------------------------------
__global__ __launch_bounds__(256)
void gemm_kernel(const unsigned short* __restrict__ A,
                 const void* __restrict__ Wb, const void* __restrict__ Wc,
                 const void* __restrict__ Wd, size_t woff,
                 const void* __restrict__ bb, const void* __restrict__ bc,
                 const void* __restrict__ bd, size_t boff,
                 float* __restrict__ C, int N, int K, int lda, int wmode,
                 const int* __restrict__ flg) {
    int isb = flg[0];
    int kgrd = (K & 31) != 0;
    __shared__ __align__(16) short Ablk[4][64][8];
    __shared__ __align__(16) short Bblk[4][64][8];
    int tid = threadIdx.x;
    int wave = tid >> 6, lane = tid & 63;
    int bm = blockIdx.y * 64, bn = blockIdx.x * 64;
    int wm = (wave & 1) * 2, wn = (wave >> 1) * 2;
    f4_t acc[2][2] = {};

    // A staging: mA = tid>>2 (row), kqA = tid&3 (k-octet); 16B direct copy.
    int mA = tid >> 2, kqA = tid & 3;
    const unsigned short* arow = A + (size_t)(bm + mA) * lda + kqA * 8;
    // B staging: col nl, k-octet kqB
    int nl = tid & 63;
    int nB = bn + nl;
    int kqB = tid >> 6;
    bool nval = nB < N;
    int ncl = nval ? nB : 0;
    const void* Wsel; size_t wcol; int wstr;
    if (wmode) {
        int which = (ncl >= 756) ? 2 : (ncl >= 378 ? 1 : 0);
        int rem = ncl - which * 378;
        int h = rem / 63, e = rem - h * 63;
        Wsel = which == 0 ? Wb : (which == 1 ? Wc : Wd);
        wcol = woff + (size_t)h * CD * 63 + e; wstr = 63;
    } else { Wsel = Wb; wcol = woff + ncl; wstr = N; }
    short* awp = &Ablk[mA >> 4][(mA & 15) | (kqA << 4)][0];
    short* bwp = &Bblk[nl >> 4][(nl & 15) | (kqB << 4)][0];

    for (int k0 = 0; k0 < K; k0 += 32) {
        *(bf8_t*)awp = *(const bf8_t*)(arow + k0);
        {
            bf8_t bv;
            #pragma unroll
            for (int jj = 0; jj < 8; jj++) {
                int kr = k0 + kqB * 8 + jj;
                float wv = 0.0f;
                if (nval && (!kgrd || kr < K))
                    wv = ldin(Wsel, wcol + (size_t)kr * wstr, isb);
                bv[jj] = (short)f2bf(wv);
            }
            *(bf8_t*)bwp = bv;
        }
        __syncthreads();
        bf8_t a0 = *(const bf8_t*)&Ablk[wm    ][lane][0];
        bf8_t a1 = *(const bf8_t*)&Ablk[wm + 1][lane][0];
        bf8_t b0 = *(const bf8_t*)&Bblk[wn    ][lane][0];
        bf8_t b1 = *(const bf8_t*)&Bblk[wn + 1][lane][0];
        acc[0][0] = __builtin_amdgcn_mfma_f32_16x16x32_bf16(a0, b0, acc[0][0], 0, 0, 0);
        acc[0][1] = __builtin_amdgcn_mfma_f32_16x16x32_bf16(a0, b1, acc[0][1], 0, 0, 0);
        acc[1][0] = __builtin_amdgcn_mfma_f32_16x16x32_bf16(a1, b0, acc[1][0], 0, 0, 0);
        acc[1][1] = __builtin_amdgcn_mfma_f32_16x16x32_bf16(a1, b1, acc[1][1], 0, 0, 0);
        __syncthreads();
    }
    int colq = lane & 15, rowq = (lane >> 4) * 4;
    #pragma unroll
    for (int ni = 0; ni < 2; ni++) {
        int col = bn + (wn + ni) * 16 + colq;
        if (col >= N) continue;
        float bbv;
        if (wmode) {
            int wh = (col >= 756) ? 2 : (col >= 378 ? 1 : 0);
            int rm = col - wh * 378;
            const void* bp = wh == 0 ? bb : (wh == 1 ? bc : bd);
            bbv = ldin(bp, boff + rm, isb);
        } else bbv = ldin(bb, boff + col, isb);
        #pragma unroll
        for (int mi = 0; mi < 2; mi++) {
            int row = bm + (wm + mi) * 16 + rowq;
            #pragma unroll
            for (int r = 0; r < 4; r++)
                C[(size_t)(row + r) * N + col] = acc[mi][ni][r] + bbv;
        }
    }
}

// ---------------------------------------------------------------------------
// add_time rows (+optional GELU). src [M,NS] fp32; dst [M,NS+1] fp32 (obf=0)
// or bf16 (obf=1).
// ---------------------------------------------------------------------------
__global__ __launch_bounds__(256)
void add_time_rows_kernel(const float* __restrict__ src, void* __restrict__ dst,
                          int NS, int do_gelu, int obf) {
    int row = blockIdx.x;
    int tid = threadIdx.x;
    __shared__ float buf[1536];
    __shared__ float red[256];
    const float* sr = src + (size_t)row * NS;
    float ss = 0.0f;
    for (int j = tid; j < NS; j += 256) {
        float vv = sr[j];
        if (do_gelu) {
            float x3 = vv * vv * vv;
            vv = 0.5f * vv * (1.0f + tanhf(0.7978845608028654f * (vv + 0.044715f * x3)));
        }
        buf[j] = vv;
        ss += vv * vv;
    }
    red[tid] = ss;
    __syncthreads();
    for (int off = 128; off > 0; off >>= 1) {
        if (tid < off) red[tid] += red[tid + off];
        __syncthreads();
    }
    float t = sqrtf(1.0f + red[0]);
    if (obf) {
        unsigned short* dr = (unsigned short*)dst + (size_t)row * (NS + 1);
        if (tid == 0) dr[0] = f2bf(t);
        for (int j = tid; j < NS; j += 256) dr[1 + j] = f2bf(buf[j]);
    } else {
        float* dr = (float*)dst + (size_t)row * (NS + 1);
        if (tid == 0) dr[0] = t;
        for (int j = tid; j < NS; j += 256) dr[1 + j] = buf[j];
    }
}

// ---------------------------------------------------------------------------
// Fused: out = lnormalize(base + scale * add_time(src)); src [M,383].
// ---------------------------------------------------------------------------
__global__ __launch_bounds__(256)
void addtime_lresnet_kernel(const float* __restrict__ src,
                            const float* __restrict__ base, float scale,
                            float* __restrict__ out) {
    int row = blockIdx.x;
    int tid = threadIdx.x;
    const float* sr = src + (size_t)row * CDS;
    const float* br = base + (size_t)row * CD;
    __shared__ float red[256];
    float s0 = (tid > 0) ? sr[tid - 1] : 0.0f;
    float s1 = (tid < 128) ? sr[tid + 255] : 0.0f;
    red[tid] = s0 * s0 + s1 * s1;
    __syncthreads();
    for (int off = 128; off > 0; off >>= 1) {
        if (tid < off) red[tid] += red[tid + off];
        __syncthreads();
    }
    float t = sqrtf(1.0f + red[0]);
    __syncthreads();
    float y0 = (tid == 0) ? t : s0;
    float z0 = br[tid] + scale * y0;
    float z1 = (tid < 128) ? br[tid + 256] + scale * s1 : 0.0f;
    float c = (tid == 0) ? z0 * z0 : -z0 * z0;
    c -= z1 * z1;
    red[tid] = c;
    __syncthreads();
    for (int off = 128; off > 0; off >>= 1) {
        if (tid < off) red[tid] += red[tid + off];
        __syncthreads();
    }
    float rd = 1.0f / sqrtf(fmaxf(red[0], 1e-8f));
    float* orow = out + (size_t)row * CD;
    orow[tid] = z0 * rd;
    if (tid < 128) orow[256 + tid] = z1 * rd;
}

// ---------------------------------------------------------------------------
// Lorentz layernorm: x[M,384] -> out fp32 [M,384] + out_bf bf16 [M,384]
// ---------------------------------------------------------------------------
__global__ __launch_bounds__(256)
void llayernorm_kernel(const float* __restrict__ x, const void* __restrict__ g,
                       size_t goff, const void* __restrict__ b, size_t boff,
                       float* __restrict__ out, unsigned short* __restrict__ out_bf,
                       const int* __restrict__ flg) {
    int isb = flg[0];
    int row = blockIdx.x;
    int tid = threadIdx.x;
    const float* xr = x + (size_t)row * CD;
    __shared__ float red[256];
    __shared__ float red2[256];
    int j0 = tid, j1 = tid + 256;
    float v0 = xr[1 + j0];
    float v1 = (j1 < CDS) ? xr[1 + j1] : 0.0f;
    red[tid]  = v0 + v1;
    red2[tid] = v0 * v0 + v1 * v1;
    __syncthreads();
    for (int off = 128; off > 0; off >>= 1) {
        if (tid < off) { red[tid] += red[tid + off]; red2[tid] += red2[tid + off]; }
        __syncthreads();
    }
    float mu  = red[0] * (1.0f / 383.0f);
    float var = red2[0] * (1.0f / 383.0f) - mu * mu;
    __syncthreads();
    float rstd = rsqrtf(var + 1e-5f);
    float y0 = (v0 - mu) * rstd * ldin(g, goff + j0, isb) + ldin(b, boff + j0, isb);
    float y1 = 0.0f;
    if (j1 < CDS) y1 = (v1 - mu) * rstd * ldin(g, goff + j1, isb) + ldin(b, boff + j1, isb);
    red[tid] = y0 * y0 + y1 * y1;
    __syncthreads();
    for (int off = 128; off > 0; off >>= 1) {
        if (tid < off) red[tid] += red[tid + off];
        __syncthreads();
    }
    float t = sqrtf(1.0f + red[0]);
    float* orow = out + (size_t)row * CD;
    unsigned short* brow = out_bf + (size_t)row * CD;
    orow[1 + j0] = y0;  brow[1 + j0] = f2bf(y0);
    if (j1 < CDS) { orow[1 + j1] = y1; brow[1 + j1] = f2bf(y1); }
    if (tid == 0) { orow[0] = t; brow[0] = f2bf(t); }
}

// lresnet vs broadcast dual-dtype pe (scale = 1)
__global__ __launch_bounds__(256)
void lresnet_pe_kernel(const float* __restrict__ x, const void* __restrict__ pe,
                       float* __restrict__ out, const int* __restrict__ flg) {
    int isb = flg[0];
    int row = blockIdx.x;
    int tid = threadIdx.x;
    const float* xr = x + (size_t)row * CD;
    size_t pb = (size_t)(row & (CN - 1)) * CD;
    __shared__ float red[256];
    float z0 = xr[tid] + ldin(pe, pb + tid, isb);
    float z1 = 0.0f;
    float c = (tid == 0) ? z0 * z0 : -z0 * z0;
    if (tid < 128) { z1 = xr[256 + tid] + ldin(pe, pb + 256 + tid, isb); c -= z1 * z1; }
    red[tid] = c;
    __syncthreads();
    for (int off = 128; off > 0; off >>= 1) {
        if (tid < off) red[tid] += red[tid + off];
        __syncthreads();
    }
    float rd = 1.0f / sqrtf(fmaxf(red[0], 1e-8f));
    float* orow = out + (size_t)row * CD;
    orow[tid] = z0 * rd;
    if (tid < 128) orow[256 + tid] = z1 * rd;
}

// ---------------------------------------------------------------------------
// qkv finish (fused): src[8192,1134] -> qkv[3][B,H,N,64] with add_time.
// grid (8192, 18): blockIdx.y = which*6 + h.
// ---------------------------------------------------------------------------
__global__ __launch_bounds__(64)
void qkv_finish_kernel(const float* __restrict__ src, float* __restrict__ qkv,
                       size_t fh) {
    int row = blockIdx.x;
    int hs  = blockIdx.y;
    int which = hs / 6, h = hs % 6;
    int e   = threadIdx.x;
    float y = (e < CHCS) ? src[(size_t)row * CQN3 + hs * 63 + e] : 0.0f;
    float ss = y * y;
    #pragma unroll
    for (int off = 32; off > 0; off >>= 1) ss += __shfl_down(ss, off);
    float t = sqrtf(1.0f + __shfl(ss, 0));
    int b = row >> 8, n = row & 255;
    float* dr = qkv + which * fh + (((size_t)(b * CH + h)) * CN + n) * CHC;
    if (e < CHCS) dr[1 + e] = y;
    if (e == 0)   dr[0] = t;
}

// ---------------------------------------------------------------------------
// Attention v4 (MFMA, split-precision). Writes attcat as bf16.
// ---------------------------------------------------------------------------
__global__ __launch_bounds__(256)
void attn_kernel(const float* __restrict__ q, const float* __restrict__ k,
                 const float* __restrict__ v, unsigned short* __restrict__ attcat) {
    __shared__ __align__(16) unsigned char smem[65536];
    unsigned short* Aqh = (unsigned short*)smem;
    unsigned short* Aql = (unsigned short*)(smem + 8192);
    unsigned short* Bk  = (unsigned short*)(smem + 16384);
    unsigned short* Pf  = (unsigned short*)smem;
    unsigned short* Bv  = (unsigned short*)(smem + 32768);
    int qc = blockIdx.x, bh = blockIdx.y;
    int h = bh % CH, b = bh / CH;
    int tid = threadIdx.x, wave = tid >> 6, lane = tid & 63;
    const float* qb = q + ((size_t)bh * CN + qc * 64) * CHC;
    const float* kb = k + (size_t)bh * CN * CHC;
    const float* vb = v + (size_t)bh * CN * CHC;

    #pragma unroll
    for (int it = 0; it < 4; it++) {
        int flat = it * 256 + tid;
        int ql = flat >> 4;
        int c4 = (flat & 15) * 4;
        float4 f = *(const float4*)(qb + ql * CHC + c4);
        if (c4 == 0) f.x = -f.x;
        int mt = ql >> 4, ks = c4 >> 5;
        int lp = (ql & 15) | (((c4 >> 3) & 3) << 4);
        int off = (((mt * 2 + ks) * 64 + lp) * 8) + (c4 & 7);
        float fv[4] = {f.x, f.y, f.z, f.w};
        #pragma unroll
        for (int i = 0; i < 4; i++) {
            unsigned short hi = f2bf(fv[i]);
            Aqh[off + i] = hi;
            Aql[off + i] = f2bf(fv[i] - bf2f(hi));
        }
    }
    #pragma unroll
    for (int it = 0; it < 16; it++) {
        int flat = it * 256 + tid;
        int tk = flat >> 4;
        int c4 = (flat & 15) * 4;
        float4 f = *(const float4*)(kb + tk * CHC + c4);
        int nt = tk >> 4, ks = c4 >> 5;
        int lp = (tk & 15) | (((c4 >> 3) & 3) << 4);
        unsigned short* dst = Bk + (((nt * 2 + ks) * 64 + lp) * 8) + (c4 & 7);
        dst[0] = f2bf(f.x); dst[1] = f2bf(f.y); dst[2] = f2bf(f.z); dst[3] = f2bf(f.w);
    }
    __syncthreads();
    f4_t s[16];
    #pragma unroll
    for (int nt = 0; nt < 16; nt++) s[nt] = (f4_t){0.0f, 0.0f, 0.0f, 0.0f};
    bf8_t ah0 = *(const bf8_t*)(Aqh + ((wave * 2 + 0) * 64 + lane) * 8);
    bf8_t ah1 = *(const bf8_t*)(Aqh + ((wave * 2 + 1) * 64 + lane) * 8);
    bf8_t al0 = *(const bf8_t*)(Aql + ((wave * 2 + 0) * 64 + lane) * 8);
    bf8_t al1 = *(const bf8_t*)(Aql + ((wave * 2 + 1) * 64 + lane) * 8);
    #pragma unroll
    for (int nt = 0; nt < 16; nt++) {
        bf8_t b0 = *(const bf8_t*)(Bk + ((nt * 2 + 0) * 64 + lane) * 8);
        bf8_t b1 = *(const bf8_t*)(Bk + ((nt * 2 + 1) * 64 + lane) * 8);
        s[nt] = __builtin_amdgcn_mfma_f32_16x16x32_bf16(ah0, b0, s[nt], 0, 0, 0);
        s[nt] = __builtin_amdgcn_mfma_f32_16x16x32_bf16(ah1, b1, s[nt], 0, 0, 0);
        s[nt] = __builtin_amdgcn_mfma_f32_16x16x32_bf16(al0, b0, s[nt], 0, 0, 0);
        s[nt] = __builtin_amdgcn_mfma_f32_16x16x32_bf16(al1, b1, s[nt], 0, 0, 0);
    }
    float mx[4] = {-1e30f, -1e30f, -1e30f, -1e30f};
    #pragma unroll
    for (int nt = 0; nt < 16; nt++)
        #pragma unroll
        for (int r = 0; r < 4; r++) mx[r] = fmaxf(mx[r], s[nt][r]);
    #pragma unroll
    for (int off = 1; off < 16; off <<= 1)
        #pragma unroll
        for (int r = 0; r < 4; r++) mx[r] = fmaxf(mx[r], __shfl_xor(mx[r], off));
    float sm[4] = {0.0f, 0.0f, 0.0f, 0.0f};
    #pragma unroll
    for (int nt = 0; nt < 16; nt++)
        #pragma unroll
        for (int r = 0; r < 4; r++) {
            float e = __expf(0.25f * (s[nt][r] - mx[r]));
            s[nt][r] = e; sm[r] += e;
        }
    #pragma unroll
    for (int off = 1; off < 16; off <<= 1)
        #pragma unroll
        for (int r = 0; r < 4; r++) sm[r] += __shfl_xor(sm[r], off);
    #pragma unroll
    for (int r = 0; r < 4; r++) sm[r] = 1.0f / sm[r];
    #pragma unroll
    for (int nt = 0; nt < 16; nt++)
        #pragma unroll
        for (int r = 0; r < 4; r++) s[nt][r] *= sm[r];

    int colq = lane & 15, quad = lane >> 4;
    auto writePf = [&](int lo) {
        #pragma unroll
        for (int nt = 0; nt < 16; nt++) {
            int key = nt * 16 + colq;
            int ks = key >> 5;
            #pragma unroll
            for (int r = 0; r < 4; r++) {
                int qrow = quad * 4 + r;
                int lp = (qrow & 15) | (((key >> 3) & 3) << 4);
                float p = s[nt][r];
                unsigned short hi = f2bf(p);
                unsigned short w = lo ? f2bf(p - bf2f(hi)) : hi;
                Pf[((wave * 8 + ks) * 64 + lp) * 8 + (key & 7)] = w;
            }
        }
    };
    auto stageBv = [&](int lo) {
        #pragma unroll
        for (int it = 0; it < 16; it++) {
            int flat = it * 256 + tid;
            int tk = flat >> 4;
            int c4 = (flat & 15) * 4;
            float4 f = *(const float4*)(vb + tk * CHC + c4);
            int ks = tk >> 5, jj = tk & 7, kq = (tk >> 3) & 3;
            int nt = c4 >> 4;
            int lq = (c4 & 15) | (kq << 4);
            unsigned short* base = Bv + ((nt * 8 + ks) * 64) * 8 + jj;
            float fv[4] = {f.x, f.y, f.z, f.w};
            #pragma unroll
            for (int i = 0; i < 4; i++) {
                unsigned short hi = f2bf(fv[i]);
                base[(lq + i) * 8] = lo ? f2bf(fv[i] - bf2f(hi)) : hi;
            }
        }
    };
    f4_t o[4] = {};
    auto pvpass = [&]() {
        #pragma unroll
        for (int ks = 0; ks < 8; ks++) {
            bf8_t pa = *(const bf8_t*)(Pf + ((wave * 8 + ks) * 64 + lane) * 8);
            #pragma unroll
            for (int nt = 0; nt < 4; nt++) {
                bf8_t vv = *(const bf8_t*)(Bv + ((nt * 8 + ks) * 64 + lane) * 8);
                o[nt] = __builtin_amdgcn_mfma_f32_16x16x32_bf16(pa, vv, o[nt], 0, 0, 0);
            }
        }
    };

    __syncthreads();
    writePf(0); stageBv(0);
    __syncthreads();
    pvpass();
    __syncthreads();
    writePf(1);
    __syncthreads();
    pvpass();
    __syncthreads();
    writePf(0); stageBv(1);
    __syncthreads();
    pvpass();

    {
        float nrm[4] = {0.0f, 0.0f, 0.0f, 0.0f};
        #pragma unroll
        for (int nt = 0; nt < 4; nt++) {
            float sgn = (nt == 0 && colq == 0) ? 1.0f : -1.0f;
            #pragma unroll
            for (int r = 0; r < 4; r++) nrm[r] += sgn * o[nt][r] * o[nt][r];
        }
        #pragma unroll
        for (int off = 1; off < 16; off <<= 1)
            #pragma unroll
            for (int r = 0; r < 4; r++) nrm[r] += __shfl_xor(nrm[r], off);
        #pragma unroll
        for (int r = 0; r < 4; r++) {
            float d = 1.0f / sqrtf(fmaxf(nrm[r], 1e-8f));
            int qg = qc * 64 + wave * 16 + quad * 4 + r;
            unsigned short* orow = attcat + ((size_t)b * CN + qg) * CD + h * CHC;
            #pragma unroll
            for (int nt = 0; nt < 4; nt++)
                orow[nt * 16 + colq] = f2bf(o[nt][r] * d);
        }
    }
}

// ---------------------------------------------------------------------------
// mean-pool over tokens + lnormalize -> emb[32,384]
// ---------------------------------------------------------------------------
__global__ __launch_bounds__(256)
void meanpool_kernel(const float* __restrict__ hbuf, float* __restrict__ emb) {
    int b = blockIdx.x;
    int tid = threadIdx.x;
    const float* hb = hbuf + (size_t)b * CN * CD;
    float s0 = 0.0f, s1 = 0.0f;
    for (int n = 0; n < CN; n++) {
        s0 += hb[(size_t)n * CD + tid];
        if (tid < 128) s1 += hb[(size_t)n * CD + 256 + tid];
    }
    s0 *= (1.0f / 256.0f);
    s1 *= (1.0f / 256.0f);
    __shared__ float red[256];
    float c = (tid == 0) ? s0 * s0 : -s0 * s0;
    if (tid < 128) c -= s1 * s1;
    red[tid] = c;
    __syncthreads();
    for (int off = 128; off > 0; off >>= 1) {
        if (tid < off) red[tid] += red[tid + off];
        __syncthreads();
    }
    float rd = 1.0f / sqrtf(fmaxf(red[0], 1e-8f));
    emb[(size_t)b * CD + tid] = s0 * rd;
    if (tid < 128) emb[(size_t)b * CD + 256 + tid] = s1 * rd;
}

// ---------------------------------------------------------------------------
// MLR head precompute v2: wave-per-class, coalesced. grid (250), 256 thr.
// ---------------------------------------------------------------------------
__global__ __launch_bounds__(256)
void head_pre_kernel(const void* __restrict__ mlra, const void* __restrict__ mlrz,
                     float* __restrict__ wt, float* __restrict__ beta,
                     float* __restrict__ cha, const int* __restrict__ flg) {
    int isb = flg[0];
    int wave = threadIdx.x >> 6, lane = threadIdx.x & 63;
    int c = blockIdx.x * 4 + wave;
    float S = 0.0f;
    for (int j = lane; j < CDS; j += 64) {
        float zz = ldin(mlrz, (size_t)c * CDS + j, isb);
        S += zz * zz;
    }
    #pragma unroll
    for (int off = 32; off > 0; off >>= 1) S += __shfl_xor(S, off);
    if (lane == 0) {
        float a  = ldin(mlra, c, isb);
        float sh = sinhf(a), ch = coshf(a);
        float zn = sqrtf(S + 1e-8f);
        float w  = sh * zn;
        wt[c]  = w;
        cha[c] = ch;
        beta[c] = sqrtf(fmaxf(ch * ch * S - w * w, 1e-8f));
    }
}

__global__ __launch_bounds__(256)
void head_logits_kernel(const float* __restrict__ emb, const void* __restrict__ mlrz,
                        const float* __restrict__ wt, const float* __restrict__ beta,
                        const float* __restrict__ cha, void* __restrict__ out,
                        const int* __restrict__ flg) {
    int isb = flg[0];
    int b = blockIdx.x;
    int c = blockIdx.y * 256 + threadIdx.x;
    __shared__ float es[CD];
    for (int j = threadIdx.x; j < CD; j += 256) es[j] = emb[(size_t)b * CD + j];
    __syncthreads();
    if (c < 1000) {
        float dotv = 0.0f;
        for (int j = 0; j < CDS; j++)
            dotv += es[1 + j] * ldin(mlrz, (size_t)c * CDS + j, isb);
        float alpha = -es[0] * wt[c] + cha[c] * dotv;
        float be = beta[c];
        float lg = be * asinhf(alpha / be);
        if (isb) ((bf16*)out)[(size_t)b * 1000 + c] = __float2bfloat16(lg);
        else     ((float*)out)[(size_t)b * 1000 + c] = lg;
    }
}

// ---------------------------------------------------------------------------
// Orchestration. Workspace (FH = 8192*384 fp32 units):
//   hbuf @0 (FH) | xln @FH (FH) | big1 @2FH (4FH) | big2 @6FH (4FH) | emb...
// bf16 overlays: patches_bf = big1; hidden_bf = big2 (2FH-worth);
// xln_bf / attcat_bf = big2+3FH (aliased, sequential lifetimes).
// ---------------------------------------------------------------------------
extern "C" void kernel_launch(void* const* d_in, const int* in_sizes, int n_in,
                              void* d_out, int out_size, void* d_ws, size_t ws_size,
                              hipStream_t stream) {
    const void* x      = d_in[0];
    const void* patchW = d_in[1];
    const void* patchB = d_in[2];
    const void* pe     = d_in[3];
    const void* ln1g   = d_in[4];
    const void* ln1b   = d_in[5];
    const void* ln2g   = d_in[6];
    const void* ln2b   = d_in[7];
    const void* Wq     = d_in[8];
    const void* bq     = d_in[9];
    const void* Wk     = d_in[10];
    const void* bk     = d_in[11];
    const void* Wv     = d_in[12];
    const void* bv     = d_in[13];
    const void* Wo     = d_in[14];
    const void* bo     = d_in[15];
    const void* W1     = d_in[16];
    const void* b1     = d_in[17];
    const void* W2     = d_in[18];
    const void* b2     = d_in[19];
    const void* mlra   = d_in[20];
    const void* mlrz   = d_in[21];

    float* ws = (float*)d_ws;
    const size_t FH = (size_t)CROWS * CD;
    float* hbuf   = ws;
    float* xln    = ws + FH;
    float* big1   = ws + 2 * FH;
    float* big2   = ws + 6 * FH;
    float* qb     = big2;
    const float* kb = big2 + FH;
    float* vb     = big2 + 2 * FH;
    unsigned short* patches_bf = (unsigned short*)big1;
    unsigned short* hidden_bf  = (unsigned short*)big2;
    unsigned short* xln_bf     = (unsigned short*)(big2 + 3 * FH);
    unsigned short* attcat_bf  = (unsigned short*)(big2 + 3 * FH);
    float* emb    = ws + 10 * FH;
    float* wt     = emb + (size_t)CB * CD;
    float* beta   = wt + 1000;
    float* cha    = beta + 1000;
    int*   flag   = (int*)(cha + 1000);

    const size_t WQKV = (size_t)CH * CD * CHCS;

    detect_kernel<<<1, 256, 0, stream>>>(x, flag);

    // patch embed (bf16 patches, stride 832)
    patchify_kernel<<<cdiv(CB * 224 * 224, 256), 256, 0, stream>>>(x, patches_bf, flag);
    padzero_kernel<<<cdiv(CROWS * (CKPP - CKP), 256), 256, 0, stream>>>(patches_bf);
    gemm_kernel<<<dim3(cdiv(CDS, 64), CROWS / 64), 256, 0, stream>>>(
        patches_bf, patchW, nullptr, nullptr, 0, patchB, nullptr, nullptr, 0,
        big2, CDS, CKP, CKPP, 0, flag);
    add_time_rows_kernel<<<CROWS, 256, 0, stream>>>(big2, xln, CDS, 0, 0);
    lresnet_pe_kernel<<<CROWS, 256, 0, stream>>>(xln, pe, hbuf, flag);

    for (int l = 0; l < CL; l++) {
        // --- attention block (residual base = LN1 output xln) ---
        llayernorm_kernel<<<CROWS, 256, 0, stream>>>(
            hbuf, ln1g, (size_t)l * CDS, ln1b, (size_t)l * CDS, xln, xln_bf, flag);
        gemm_kernel<<<dim3(cdiv(CQN3, 64), CROWS / 64), 256, 0, stream>>>(
            xln_bf, Wq, Wk, Wv, (size_t)l * WQKV, bq, bk, bv, (size_t)l * CQN,
            big1, CQN3, CD, CD, 1, flag);
        qkv_finish_kernel<<<dim3(CROWS, 18), 64, 0, stream>>>(big1, qb, FH);
        attn_kernel<<<dim3(4, CB * CH), 256, 0, stream>>>(qb, kb, vb, attcat_bf);
        gemm_kernel<<<dim3(cdiv(CDS, 64), CROWS / 64), 256, 0, stream>>>(
            attcat_bf, Wo, nullptr, nullptr, (size_t)l * CD * CDS,
            bo, nullptr, nullptr, (size_t)l * CDS, big1, CDS, CD, CD, 0, flag);
        addtime_lresnet_kernel<<<CROWS, 256, 0, stream>>>(big1, xln, 27.5f, hbuf);
        // --- mlp block (residual base = hbuf) ---
        llayernorm_kernel<<<CROWS, 256, 0, stream>>>(
            hbuf, ln2g, (size_t)l * CDS, ln2b, (size_t)l * CDS, xln, xln_bf, flag);
        gemm_kernel<<<dim3(cdiv(CMHS, 64), CROWS / 64), 256, 0, stream>>>(
            xln_bf, W1, nullptr, nullptr, (size_t)l * CD * CMHS,
            b1, nullptr, nullptr, (size_t)l * CMHS, big1, CMHS, CD, CD, 0, flag);
        add_time_rows_kernel<<<CROWS, 256, 0, stream>>>(big1, hidden_bf, CMHS, 1, 1);
        gemm_kernel<<<dim3(cdiv(CDS, 64), CROWS / 64), 256, 0, stream>>>(
            hidden_bf, W2, nullptr, nullptr, (size_t)l * CMH * CDS,
            b2, nullptr, nullptr, (size_t)l * CDS, big1, CDS, CMH, CMH, 0, flag);
        addtime_lresnet_kernel<<<CROWS, 256, 0, stream>>>(big1, hbuf, 27.5f, hbuf);
    }

    // head
    meanpool_kernel<<<CB, 256, 0, stream>>>(hbuf, emb);
    head_pre_kernel<<<250, 256, 0, stream>>>(mlra, mlrz, wt, beta, cha, flag);
    head_logits_kernel<<<dim3(CB, 4), 256, 0, stream>>>(emb, mlrz, wt, beta, cha, d_out, flag);
}